// Round 15
// baseline (276.055 us; speedup 1.0000x reference)
//
#include <hip/hip_runtime.h>
#include <hip/hip_fp16.h>
#include <math.h>

// SSL compressor gain: 128 independent nonlinear 2-state IIR chains, T=131072.
// Round 15: NIT back to 3 (r14 falsified the quadratic contraction model:
// exact-Newton contracts ~0.43/iter independent of CF -> 3 iters mandatory
// with 4x-decim map guesses). Speed attack moves to per-pass cost:
//   - ssl_tr: one-time corner-turn of x into x_t[blk][chunk] (float4 = 4
//     steps of one chunk) -> every wave load in jac/out is 1KB contiguous
//     (r13's 39us/pass was transaction-bound on 16B/lane strided loads,
//     VALUBusy 24%, HBM 1.5 TB/s). Also emits xq (quad sums) for the map.
//   - ssl_map_q: reads xq (4x fewer loads, no sum adds) - pure issue-bound.
//   - ssl_row: wave-shfl affine scan (3 barriers/iter vs 11) + coalesced
//     x_t reads. Math identical to r13 except scan reassociation (~1e-6).
//   - Fallback (ws too small): r13-style strided path, template<bool>.

constexpr int   T_LEN    = 131072;
constexpr int   NCM      = 64;              // coarse map chunks
constexpr int   CM       = T_LEN / NCM;     // 2048 samples
constexpr int   SUB      = 16;              // snapshots per map chunk (every 128)
constexpr int   NC       = NCM * SUB;       // 1024 fine chunks
constexpr int   CF       = T_LEN / NC;      // 128 samples
constexpr int   K        = 16;              // ES nodes: 0 .. -8, h=8/15
constexpr float STEP_ES  = 8.0f / 15.0f;
constexpr float INV_STEP = 15.0f / 8.0f;
constexpr int   DPF      = 8;
constexpr int   NV_ROW   = T_LEN >> 2;      // 32768 float4 per row
constexpr int   QROW     = T_LEN >> 2;      // 32768 quad sums per row
constexpr int   NIT      = 3;               // exact Newton iterations (r13-proven)
constexpr int   LINK     = NCM * K;         // 1024

// pw: 0 nhs, 1 hst, 2 nq, 3 r, 4..7 a_{af,as,sf,ss}, 8..11 a^4, 12 nhs_q
__global__ void ssl_params_k(
        float* __restrict__ pw,
        const float* cth, const float* rl, const float* fbl,
        const float* uaf, const float* uas, const float* usf, const float* uss)
{
    const double FS = 44100.0;
    const double T_AF_MIN = 820.0 * 4.7e-07 * 0.8,   T_AF_MAX = 270000.0 * 4.7e-07 * 1.2;
    const double T_AS_MIN = 820.0 * 6.8e-06 * 0.8,   T_AS_MAX = 270000.0 * 6.8e-06 * 100.0;
    const double T_SF_MIN = 91000.0 * 4.7e-07 * 0.8, T_SF_MAX = 1200000.0 * 4.7e-07 * 1.2;
    const double T_SS_MIN = 750000.0 * 6.8e-06 * 0.8, T_SS_MAX = 750000.0 * 6.8e-06 * 100.0;

    double cr    = fmax(exp((double)rl[0]) + 1.0, 1.0 + 1e-4);
    double fb    = 1.0 / (1.0 + exp(-(double)fbl[0]));
    double slope = 1.0 - 1.0 / cr;

    double s_af = T_AF_MIN + (T_AF_MAX - T_AF_MIN) / (1.0 + exp(-(double)uaf[0]));
    double s_as = T_AS_MIN + (T_AS_MAX - T_AS_MIN) / (1.0 + exp(-(double)uas[0]));
    double s_sf = T_SF_MIN + (T_SF_MAX - T_SF_MIN) / (1.0 + exp(-(double)usf[0]));
    double s_ss = T_SS_MIN + (T_SS_MAX - T_SS_MIN) / (1.0 + exp(-(double)uss[0]));

    float a_af = (float)exp(-1.0 / (FS * s_af));
    float a_as = (float)exp(-1.0 / (FS * s_as));
    float a_sf = (float)exp(-1.0 / (FS * s_sf));
    float a_ss = (float)exp(-1.0 / (FS * s_ss));
    double q = 0.5 * slope * fb;

    pw[0]  = (float)(-0.5 * slope);
    pw[1]  = (float)(0.5 * slope * (double)cth[0]);
    pw[2]  = (float)(-q);
    pw[3]  = (float)(0.5 + q);
    pw[4]  = a_af;  pw[5] = a_as;  pw[6] = a_sf;  pw[7] = a_ss;
    float e_af = a_af * a_af, e_as = a_as * a_as, e_sf = a_sf * a_sf, e_ss = a_ss * a_ss;
    pw[8]  = e_af * e_af;  pw[9]  = e_as * e_as;   // a^4
    pw[10] = e_sf * e_sf;  pw[11] = e_ss * e_ss;
    pw[12] = (float)(-0.125 * slope);              // quad-avg input coef
}

// Corner-turn: x_t[b][blk][c] (float4 = steps blk*4..+3 of fine chunk c) and
// xq[b][i] = pairwise quad sum of x[4i..4i+3] (same assoc as r13's map).
__global__ __launch_bounds__(256) void ssl_tr(
        const float* __restrict__ x, float* __restrict__ xt,
        float* __restrict__ xq)
{
    __shared__ float lds[64][129];
    const int b = blockIdx.x >> 1;
    const int h = blockIdx.x & 1;
    const int tid = threadIdx.x;
    const float4* __restrict__ x4 = reinterpret_cast<const float4*>(x) + (size_t)b * NV_ROW;
    float4* __restrict__ xt4      = reinterpret_cast<float4*>(xt) + (size_t)b * NV_ROW;
    float* __restrict__ xqr       = xq + (size_t)b * QROW;

    for (int tile = h * 8; tile < h * 8 + 8; ++tile) {
        const int c0 = tile * 64;                      // 64 chunks per tile
        #pragma unroll
        for (int it = 0; it < 8; ++it) {               // load 64x128 floats
            int idx = it * 256 + tid;                  // 0..2047 float4
            int c = idx >> 5, s4 = idx & 31;
            float4 v = x4[(size_t)(c0 + c) * 32 + s4];
            lds[c][s4 * 4 + 0] = v.x; lds[c][s4 * 4 + 1] = v.y;
            lds[c][s4 * 4 + 2] = v.z; lds[c][s4 * 4 + 3] = v.w;
        }
        __syncthreads();
        #pragma unroll
        for (int it = 0; it < 8; ++it) {               // transposed x_t store
            int idx = it * 256 + tid;
            int blk = idx >> 6, c = idx & 63;
            float4 w;
            w.x = lds[c][blk * 4 + 0]; w.y = lds[c][blk * 4 + 1];
            w.z = lds[c][blk * 4 + 2]; w.w = lds[c][blk * 4 + 3];
            xt4[(size_t)blk * 1024 + c0 + c] = w;
        }
        #pragma unroll
        for (int it = 0; it < 8; ++it) {               // quad sums
            int qi = it * 256 + tid;                   // 0..2047
            int cc = qi >> 5, off = (qi & 31) * 4;
            float s = (lds[cc][off] + lds[cc][off + 1]) + (lds[cc][off + 2] + lds[cc][off + 3]);
            xqr[c0 * 32 + qi] = s;
        }
        __syncthreads();
    }
}

// 4x-decimated diagonal chunk maps reading precomputed quad sums.
__global__ __launch_bounds__(256) void ssl_map_q(
        const float* __restrict__ xq, __half2* __restrict__ mp,
        const float* __restrict__ pw, int B)
{
    int tid = blockIdx.x * 256 + threadIdx.x;
    int k  = tid & (K - 1);
    int bc = tid >> 4;
    if (bc >= B * NCM) return;
    int c  = bc & (NCM - 1);
    int b  = bc >> 6;

    const float nhs_q = pw[12], hst = pw[1], nq = pw[2], r = pw[3];
    const float e_af = pw[8], e_as = pw[9], e_sf = pw[10], e_ss = pw[11];

    float v0s = -STEP_ES * (float)k;
    float EF = v0s, ES = v0s, Y = EF + ES;
    const float4* __restrict__ q4 =
        reinterpret_cast<const float4*>(xq) + (size_t)b * (QROW >> 2) + (size_t)c * (CM >> 4);

    float4 buf[DPF];
    #pragma unroll
    for (int i = 0; i < DPF; ++i) buf[i] = q4[i];

    #pragma unroll 1
    for (int q16 = 0; q16 < SUB; ++q16) {
        for (int v = 0; v < 8; ++v) {                  // 8 float4 = 32 q-steps
            int idx = q16 * 8 + v;
            float4 xv = buf[idx & 7];
            int nxt = idx + 8;
            if (nxt < (CM >> 4)) buf[idx & 7] = q4[nxt];
#define QSTEP(XS) { \
            float sx2 = fmaf(nhs_q, (XS), hst); \
            float u2  = fmaf(nq, Y, sx2); \
            float t2  = fminf(u2, 0.0f); \
            bool att  = sx2 < r * Y; \
            float af  = att ? e_af : e_sf; \
            float as2 = att ? e_as : e_ss; \
            EF = fmaf(af,  EF - t2, t2); \
            ES = fmaf(as2, ES - t2, t2); \
            Y  = EF + ES; }
            QSTEP(xv.x) QSTEP(xv.y) QSTEP(xv.z) QSTEP(xv.w)
#undef QSTEP
        }
        mp[((size_t)bc * SUB + q16) * K + k] = __floats2half2_rn(EF, ES);
    }
}

// Fallback map reading x directly (r13-identical).
__global__ __launch_bounds__(256) void ssl_map_x(
        const float* __restrict__ x, __half2* __restrict__ mp,
        const float* __restrict__ pw, int B)
{
    int tid = blockIdx.x * 256 + threadIdx.x;
    int k  = tid & (K - 1);
    int bc = tid >> 4;
    if (bc >= B * NCM) return;
    int c  = bc & (NCM - 1);
    int b  = bc >> 6;

    const float nhs_q = pw[12], hst = pw[1], nq = pw[2], r = pw[3];
    const float e_af = pw[8], e_as = pw[9], e_sf = pw[10], e_ss = pw[11];

    float v0s = -STEP_ES * (float)k;
    float EF = v0s, ES = v0s, Y = EF + ES;
    const float4* __restrict__ xr = reinterpret_cast<const float4*>(x) + (size_t)b * NV_ROW;
    const int v0 = c * (CM >> 2);

    float4 buf[DPF];
    #pragma unroll
    for (int i = 0; i < DPF; ++i) buf[i] = xr[v0 + i];

    #pragma unroll 1
    for (int q16 = 0; q16 < SUB; ++q16) {
        const int s0 = v0 + q16 * (CF >> 2);
        for (int v = s0; v < s0 + (CF >> 2); v += DPF) {
            #pragma unroll
            for (int i = 0; i < DPF; ++i) {
                float4 xv = buf[i];
                int nxt = v + DPF + i;
                if (nxt < NV_ROW) buf[i] = xr[nxt];
                float s = (xv.x + xv.y) + (xv.z + xv.w);
                float sx2 = fmaf(nhs_q, s, hst);
                float u2  = fmaf(nq, Y, sx2);
                float t2  = fminf(u2, 0.0f);
                bool att  = sx2 < r * Y;
                float af  = att ? e_af : e_sf;
                float as2 = att ? e_as : e_ss;
                EF = fmaf(af,  EF - t2, t2);
                ES = fmaf(as2, ES - t2, t2);
                Y  = EF + ES;
            }
        }
        mp[((size_t)bc * SUB + q16) * K + k] = __floats2half2_rn(EF, ES);
    }
}

// Per-row block: link-stage -> compose0 -> 3x exact Newton (jac + shfl scan)
// -> exact out. XT: coalesced x_t reads; else r13 strided reads.
template<bool XT>
__global__ __launch_bounds__(1024) void ssl_row_k(
        const float* __restrict__ x, const float* __restrict__ xt,
        float* __restrict__ out,
        const __half2* __restrict__ mp, const float* __restrict__ pw, int B)
{
    __shared__ __half2 link_s[LINK];                 // 4 KB
    __shared__ float2 bnd_s[NC];                     // 8 KB
    __shared__ float4 aggJ[16];
    __shared__ float2 aggG[16];

    const int b = blockIdx.x;
    const int t = threadIdx.x;                       // 0..1023
    const int lane = t & 63, w = t >> 6;

    const float nhs = pw[0], hst = pw[1], nq = pw[2], r = pw[3];
    const float a_af = pw[4], a_as = pw[5], a_sf = pw[6], a_ss = pw[7];

    const float4* __restrict__ base4 =
        reinterpret_cast<const float4*>(XT ? xt : x) + (size_t)b * NV_ROW;

    // ---- stage link slice ----
    {
        int c = t >> 4, k = t & 15;
        link_s[t] = mp[((size_t)(b * NCM + c) * SUB + (SUB - 1)) * K + k];
    }
    __syncthreads();

    // ---- compose0 serial on LDS (thread 0) ----
    if (t == 0) {
        float EF = 0.0f, ES = 0.0f;
        for (int c = 0; c < NCM; ++c) {
            bnd_s[SUB * c] = make_float2(EF, ES);
            float tt = -ES * INV_STEP;
            int idx = (int)tt;
            idx = idx < 0 ? 0 : (idx > K - 2 ? K - 2 : idx);
            float u = tt - (float)idx;
            float2 a0 = __half22float2(link_s[c * K + idx]);
            float2 a1 = __half22float2(link_s[c * K + idx + 1]);
            EF = a0.x + (a1.x - a0.x) * u;
            ES = a0.y + (a1.y - a0.y) * u;
        }
    }
    __syncthreads();
    // ---- parallel snapshot guesses ----
    {
        int c = t >> 4, j = t & 15;
        if (j > 0) {
            float ES = bnd_s[SUB * c].y;
            float tt = -ES * INV_STEP;
            int idx = (int)tt;
            idx = idx < 0 ? 0 : (idx > K - 2 ? K - 2 : idx);
            float u = tt - (float)idx;
            const __half2* m = mp + ((size_t)(b * NCM + c) * SUB + (j - 1)) * K;
            float2 a0 = __half22float2(m[idx]);
            float2 a1 = __half22float2(m[idx + 1]);
            bnd_s[t] = make_float2(a0.x + (a1.x - a0.x) * u,
                                   a0.y + (a1.y - a0.y) * u);
        }
    }
    __syncthreads();

    // ---- 3x exact Newton: jac -> wave-shfl affine scan ----
    #pragma unroll 1
    for (int it = 0; it < NIT; ++it) {
        float2 s0 = bnd_s[t];
        float EF = s0.x, ES = s0.y, Y = EF + ES;
        float jFx = 1.0f, jFy = 0.0f, jSx = 0.0f, jSy = 1.0f;

        float4 buf[DPF];
        #pragma unroll
        for (int i = 0; i < DPF; ++i)
            buf[i] = base4[XT ? ((size_t)i * 1024 + t) : ((size_t)t * 32 + i)];

        #pragma unroll 1
        for (int blk = 0; blk < 32; ++blk) {
            float4 xv = buf[blk & 7];
            int nxt = blk + 8;
            if (nxt < 32)
                buf[blk & 7] = base4[XT ? ((size_t)nxt * 1024 + t) : ((size_t)t * 32 + nxt)];
#define SSL_STEP_J(XV) { \
            float sx2 = fmaf(nhs, (XV), hst); \
            float u2  = fmaf(nq, Y, sx2); \
            float t2  = fminf(u2, 0.0f); \
            float mm  = (u2 < 0.0f) ? nq : 0.0f; \
            bool att  = sx2 < r * Y; \
            float af  = att ? a_af : a_sf; \
            float as2 = att ? a_as : a_ss; \
            float jtx = mm * (jFx + jSx); \
            float jty = mm * (jFy + jSy); \
            jFx = fmaf(af,  jFx - jtx, jtx); \
            jFy = fmaf(af,  jFy - jty, jty); \
            jSx = fmaf(as2, jSx - jtx, jtx); \
            jSy = fmaf(as2, jSy - jty, jty); \
            EF  = fmaf(af,  EF - t2, t2); \
            ES  = fmaf(as2, ES - t2, t2); \
            Y   = EF + ES; }
            SSL_STEP_J(xv.x)
            SSL_STEP_J(xv.y)
            SSL_STEP_J(xv.z)
            SSL_STEP_J(xv.w)
#undef SSL_STEP_J
        }
        float gx = EF - (jFx * s0.x + jFy * s0.y);
        float gy = ES - (jSx * s0.x + jSy * s0.y);

        // in-wave inclusive scan of affine maps (self = self ∘ prev)
        for (int d = 1; d < 64; d <<= 1) {
            float pa = __shfl_up(jFx, d), pb = __shfl_up(jFy, d);
            float pc = __shfl_up(jSx, d), pd = __shfl_up(jSy, d);
            float px = __shfl_up(gx, d),  py = __shfl_up(gy, d);
            if (lane >= d) {
                float na = jFx * pa + jFy * pc, nb = jFx * pb + jFy * pd;
                float nc = jSx * pa + jSy * pc, nd = jSx * pb + jSy * pd;
                gx = jFx * px + jFy * py + gx;
                gy = jSx * px + jSy * py + gy;
                jFx = na; jFy = nb; jSx = nc; jSy = nd;
            }
        }
        if (lane == 63) {
            aggJ[w] = make_float4(jFx, jFy, jSx, jSy);
            aggG[w] = make_float2(gx, gy);
        }
        __syncthreads();
        if (t < 16) {                                // scan 16 wave aggregates
            float4 J = aggJ[t]; float2 g = aggG[t];
            float a = J.x, bb = J.y, c = J.z, dd = J.w, ggx = g.x, ggy = g.y;
            for (int d = 1; d < 16; d <<= 1) {
                float pa = __shfl_up(a, d), pb = __shfl_up(bb, d);
                float pc = __shfl_up(c, d), pd = __shfl_up(dd, d);
                float px = __shfl_up(ggx, d), py = __shfl_up(ggy, d);
                if (t >= d) {
                    float na = a * pa + bb * pc, nb = a * pb + bb * pd;
                    float nc = c * pa + dd * pc, nd = c * pb + dd * pd;
                    ggx = a * px + bb * py + ggx;
                    ggy = c * px + dd * py + ggy;
                    a = na; bb = nb; c = nc; dd = nd;
                }
            }
            aggJ[t] = make_float4(a, bb, c, dd);
            aggG[t] = make_float2(ggx, ggy);
        }
        __syncthreads();
        float2 send;
        if (w == 0) send = make_float2(gx, gy);
        else {
            float2 pg = aggG[w - 1];
            send = make_float2(jFx * pg.x + jFy * pg.y + gx,
                               jSx * pg.x + jSy * pg.y + gy);
        }
        if (t < NC - 1) bnd_s[t + 1] = send;
        else           bnd_s[0] = make_float2(0.0f, 0.0f);
        __syncthreads();
    }

    // ---- out: exact rerun, store y ----
    {
        float2 s = bnd_s[t];
        float EF = s.x, ES = s.y, Y = EF + ES;
        float4* __restrict__ yr = reinterpret_cast<float4*>(out) + (size_t)b * NV_ROW;

        float4 buf[DPF];
        #pragma unroll
        for (int i = 0; i < DPF; ++i)
            buf[i] = base4[XT ? ((size_t)i * 1024 + t) : ((size_t)t * 32 + i)];

        #pragma unroll 1
        for (int blk = 0; blk < 32; ++blk) {
            float4 xv = buf[blk & 7];
            int nxt = blk + 8;
            if (nxt < 32)
                buf[blk & 7] = base4[XT ? ((size_t)nxt * 1024 + t) : ((size_t)t * 32 + nxt)];
            float4 yo;
#define SSL_STEP(XV, YOUT) { \
            float sx2 = fmaf(nhs, (XV), hst); \
            float u2  = fmaf(nq, Y, sx2); \
            float t2  = fminf(u2, 0.0f); \
            bool att  = sx2 < r * Y; \
            float af  = att ? a_af : a_sf; \
            float as2 = att ? a_as : a_ss; \
            EF = fmaf(af,  EF - t2, t2); \
            ES = fmaf(as2, ES - t2, t2); \
            Y  = EF + ES; \
            (YOUT) = Y; }
            SSL_STEP(xv.x, yo.x)
            SSL_STEP(xv.y, yo.y)
            SSL_STEP(xv.z, yo.z)
            SSL_STEP(xv.w, yo.w)
#undef SSL_STEP
            yr[(size_t)t * 32 + blk] = yo;
        }
    }
}

extern "C" void kernel_launch(void* const* d_in, const int* in_sizes, int n_in,
                              void* d_out, int out_size, void* d_ws, size_t ws_size,
                              hipStream_t stream) {
    const float* x = (const float*)d_in[0];
    const int B = in_sizes[0] / T_LEN;   // 128

    // ws layout: mp | pw(256B) | xq | xt
    const size_t MP_B = (size_t)B * NCM * SUB * K * sizeof(__half2);   // 8 MB
    const size_t PW_O = MP_B;
    const size_t XQ_O = PW_O + 256;
    const size_t XQ_B = (size_t)B * QROW * sizeof(float);              // 16 MB
    const size_t XT_O = XQ_O + XQ_B;
    const size_t XT_B = (size_t)B * T_LEN * sizeof(float);             // 64 MB
    const bool fast = ws_size >= XT_O + XT_B;

    __half2* mp = (__half2*)d_ws;
    float*   pw = (float*)((char*)d_ws + PW_O);
    float*   xq = (float*)((char*)d_ws + XQ_O);
    float*   xt = (float*)((char*)d_ws + XT_O);

    ssl_params_k<<<1, 1, 0, stream>>>(
        pw,
        (const float*)d_in[1], (const float*)d_in[2], (const float*)d_in[3],
        (const float*)d_in[4], (const float*)d_in[5], (const float*)d_in[6],
        (const float*)d_in[7]);

    int map_blocks = (B * NCM * K + 255) / 256;     // 512
    if (fast) {
        ssl_tr<<<2 * B, 256, 0, stream>>>(x, xt, xq);
        ssl_map_q<<<map_blocks, 256, 0, stream>>>(xq, mp, pw, B);
        ssl_row_k<true><<<B, 1024, 0, stream>>>(x, xt, (float*)d_out, mp, pw, B);
    } else {
        ssl_map_x<<<map_blocks, 256, 0, stream>>>(x, mp, pw, B);
        ssl_row_k<false><<<B, 1024, 0, stream>>>(x, nullptr, (float*)d_out, mp, pw, B);
    }
}

// Round 16
// 203.911 us; speedup vs baseline: 1.3538x; 1.3538x over previous
//
#include <hip/hip_runtime.h>
#include <hip/hip_fp16.h>
#include <math.h>

// SSL compressor gain: 128 independent nonlinear 2-state IIR chains, T=131072.
// Round 16: r15 with the scratch-spill bug fixed.
//   r15 post-mortem: jac/out loops used buf[blk & 7] under #pragma unroll 1 ->
//   runtime-indexed array -> SCRATCH (VGPR 64->44, WRITE_SIZE 78->429 MB,
//   ssl_row became spill-write-bound at 217us). Fix: r13 loop shape (outer
//   step DPF, inner #pragma unroll, buf[i] static). All else = r15:
//   corner-turned x_t (coalesced 1KB/wave loads), xq quad-sum map input,
//   wave-shfl affine scan, NIT=3 exact Newton (absmax 0.125 proven).

constexpr int   T_LEN    = 131072;
constexpr int   NCM      = 64;              // coarse map chunks
constexpr int   CM       = T_LEN / NCM;     // 2048 samples
constexpr int   SUB      = 16;              // snapshots per map chunk (every 128)
constexpr int   NC       = NCM * SUB;       // 1024 fine chunks
constexpr int   CF       = T_LEN / NC;      // 128 samples
constexpr int   K        = 16;              // ES nodes: 0 .. -8, h=8/15
constexpr float STEP_ES  = 8.0f / 15.0f;
constexpr float INV_STEP = 15.0f / 8.0f;
constexpr int   DPF      = 8;
constexpr int   NV_ROW   = T_LEN >> 2;      // 32768 float4 per row
constexpr int   QROW     = T_LEN >> 2;      // 32768 quad sums per row
constexpr int   NIT      = 3;               // exact Newton iterations (r13-proven)
constexpr int   LINK     = NCM * K;         // 1024

// pw: 0 nhs, 1 hst, 2 nq, 3 r, 4..7 a_{af,as,sf,ss}, 8..11 a^4, 12 nhs_q
__global__ void ssl_params_k(
        float* __restrict__ pw,
        const float* cth, const float* rl, const float* fbl,
        const float* uaf, const float* uas, const float* usf, const float* uss)
{
    const double FS = 44100.0;
    const double T_AF_MIN = 820.0 * 4.7e-07 * 0.8,   T_AF_MAX = 270000.0 * 4.7e-07 * 1.2;
    const double T_AS_MIN = 820.0 * 6.8e-06 * 0.8,   T_AS_MAX = 270000.0 * 6.8e-06 * 100.0;
    const double T_SF_MIN = 91000.0 * 4.7e-07 * 0.8, T_SF_MAX = 1200000.0 * 4.7e-07 * 1.2;
    const double T_SS_MIN = 750000.0 * 6.8e-06 * 0.8, T_SS_MAX = 750000.0 * 6.8e-06 * 100.0;

    double cr    = fmax(exp((double)rl[0]) + 1.0, 1.0 + 1e-4);
    double fb    = 1.0 / (1.0 + exp(-(double)fbl[0]));
    double slope = 1.0 - 1.0 / cr;

    double s_af = T_AF_MIN + (T_AF_MAX - T_AF_MIN) / (1.0 + exp(-(double)uaf[0]));
    double s_as = T_AS_MIN + (T_AS_MAX - T_AS_MIN) / (1.0 + exp(-(double)uas[0]));
    double s_sf = T_SF_MIN + (T_SF_MAX - T_SF_MIN) / (1.0 + exp(-(double)usf[0]));
    double s_ss = T_SS_MIN + (T_SS_MAX - T_SS_MIN) / (1.0 + exp(-(double)uss[0]));

    float a_af = (float)exp(-1.0 / (FS * s_af));
    float a_as = (float)exp(-1.0 / (FS * s_as));
    float a_sf = (float)exp(-1.0 / (FS * s_sf));
    float a_ss = (float)exp(-1.0 / (FS * s_ss));
    double q = 0.5 * slope * fb;

    pw[0]  = (float)(-0.5 * slope);
    pw[1]  = (float)(0.5 * slope * (double)cth[0]);
    pw[2]  = (float)(-q);
    pw[3]  = (float)(0.5 + q);
    pw[4]  = a_af;  pw[5] = a_as;  pw[6] = a_sf;  pw[7] = a_ss;
    float e_af = a_af * a_af, e_as = a_as * a_as, e_sf = a_sf * a_sf, e_ss = a_ss * a_ss;
    pw[8]  = e_af * e_af;  pw[9]  = e_as * e_as;   // a^4
    pw[10] = e_sf * e_sf;  pw[11] = e_ss * e_ss;
    pw[12] = (float)(-0.125 * slope);              // quad-avg input coef
}

// Corner-turn: x_t[b][blk][c] (float4 = steps blk*4..+3 of fine chunk c) and
// xq[b][i] = pairwise quad sum of x[4i..4i+3].
__global__ __launch_bounds__(256) void ssl_tr(
        const float* __restrict__ x, float* __restrict__ xt,
        float* __restrict__ xq)
{
    __shared__ float lds[64][129];
    const int b = blockIdx.x >> 1;
    const int h = blockIdx.x & 1;
    const int tid = threadIdx.x;
    const float4* __restrict__ x4 = reinterpret_cast<const float4*>(x) + (size_t)b * NV_ROW;
    float4* __restrict__ xt4      = reinterpret_cast<float4*>(xt) + (size_t)b * NV_ROW;
    float* __restrict__ xqr       = xq + (size_t)b * QROW;

    for (int tile = h * 8; tile < h * 8 + 8; ++tile) {
        const int c0 = tile * 64;                      // 64 chunks per tile
        #pragma unroll
        for (int it = 0; it < 8; ++it) {               // load 64x128 floats
            int idx = it * 256 + tid;                  // 0..2047 float4
            int c = idx >> 5, s4 = idx & 31;
            float4 v = x4[(size_t)(c0 + c) * 32 + s4];
            lds[c][s4 * 4 + 0] = v.x; lds[c][s4 * 4 + 1] = v.y;
            lds[c][s4 * 4 + 2] = v.z; lds[c][s4 * 4 + 3] = v.w;
        }
        __syncthreads();
        #pragma unroll
        for (int it = 0; it < 8; ++it) {               // transposed x_t store
            int idx = it * 256 + tid;
            int blk = idx >> 6, c = idx & 63;
            float4 w;
            w.x = lds[c][blk * 4 + 0]; w.y = lds[c][blk * 4 + 1];
            w.z = lds[c][blk * 4 + 2]; w.w = lds[c][blk * 4 + 3];
            xt4[(size_t)blk * 1024 + c0 + c] = w;
        }
        #pragma unroll
        for (int it = 0; it < 8; ++it) {               // quad sums
            int qi = it * 256 + tid;                   // 0..2047
            int cc = qi >> 5, off = (qi & 31) * 4;
            float s = (lds[cc][off] + lds[cc][off + 1]) + (lds[cc][off + 2] + lds[cc][off + 3]);
            xqr[c0 * 32 + qi] = s;
        }
        __syncthreads();
    }
}

// 4x-decimated diagonal chunk maps reading precomputed quad sums.
__global__ __launch_bounds__(256) void ssl_map_q(
        const float* __restrict__ xq, __half2* __restrict__ mp,
        const float* __restrict__ pw, int B)
{
    int tid = blockIdx.x * 256 + threadIdx.x;
    int k  = tid & (K - 1);
    int bc = tid >> 4;
    if (bc >= B * NCM) return;
    int c  = bc & (NCM - 1);
    int b  = bc >> 6;

    const float nhs_q = pw[12], hst = pw[1], nq = pw[2], r = pw[3];
    const float e_af = pw[8], e_as = pw[9], e_sf = pw[10], e_ss = pw[11];

    float v0s = -STEP_ES * (float)k;
    float EF = v0s, ES = v0s, Y = EF + ES;
    const float4* __restrict__ q4 =
        reinterpret_cast<const float4*>(xq) + (size_t)b * (QROW >> 2) + (size_t)c * (CM >> 4);

    float4 buf[DPF];
    #pragma unroll
    for (int i = 0; i < DPF; ++i) buf[i] = q4[i];

    #pragma unroll 1
    for (int q16 = 0; q16 < SUB; q16 += 2) {           // 2 sub-segments = 16 q4
        #pragma unroll
        for (int half = 0; half < 2; ++half) {
            #pragma unroll
            for (int i = half * 4; i < half * 4 + 4; ++i) {  // 4 float4 each... 
                // NOTE: 8 q-steps per snapshot -> one snapshot per 2 float4.
            }
        }
        // Simpler explicit form below (kept linear for clarity):
        #pragma unroll
        for (int i = 0; i < DPF; ++i) {
            float4 xv = buf[i];
            int base = (q16 >> 1) * DPF;               // consumed q4 so far
            int nxt = base + DPF + i;
            if (nxt < (CM >> 4)) buf[i] = q4[nxt];
#define QSTEP(XS) { \
            float sx2 = fmaf(nhs_q, (XS), hst); \
            float u2  = fmaf(nq, Y, sx2); \
            float t2  = fminf(u2, 0.0f); \
            bool att  = sx2 < r * Y; \
            float af  = att ? e_af : e_sf; \
            float as2 = att ? e_as : e_ss; \
            EF = fmaf(af,  EF - t2, t2); \
            ES = fmaf(as2, ES - t2, t2); \
            Y  = EF + ES; }
            QSTEP(xv.x) QSTEP(xv.y) QSTEP(xv.z) QSTEP(xv.w)
#undef QSTEP
            if (i == 3) mp[((size_t)bc * SUB + q16) * K + k] = __floats2half2_rn(EF, ES);
        }
        mp[((size_t)bc * SUB + q16 + 1) * K + k] = __floats2half2_rn(EF, ES);
    }
}

// Per-row block: link-stage -> compose0 -> 3x exact Newton (jac + shfl scan)
// -> exact out. Coalesced x_t reads (float4 = 4 steps of chunk t at blk i).
__global__ __launch_bounds__(1024) void ssl_row_k(
        const float* __restrict__ xt, float* __restrict__ out,
        const __half2* __restrict__ mp, const float* __restrict__ pw, int B)
{
    __shared__ __half2 link_s[LINK];                 // 4 KB
    __shared__ float2 bnd_s[NC];                     // 8 KB
    __shared__ float4 aggJ[16];
    __shared__ float2 aggG[16];

    const int b = blockIdx.x;
    const int t = threadIdx.x;                       // 0..1023
    const int lane = t & 63, w = t >> 6;

    const float nhs = pw[0], hst = pw[1], nq = pw[2], r = pw[3];
    const float a_af = pw[4], a_as = pw[5], a_sf = pw[6], a_ss = pw[7];

    const float4* __restrict__ base4 =
        reinterpret_cast<const float4*>(xt) + (size_t)b * NV_ROW;

    // ---- stage link slice ----
    {
        int c = t >> 4, k = t & 15;
        link_s[t] = mp[((size_t)(b * NCM + c) * SUB + (SUB - 1)) * K + k];
    }
    __syncthreads();

    // ---- compose0 serial on LDS (thread 0) ----
    if (t == 0) {
        float EF = 0.0f, ES = 0.0f;
        for (int c = 0; c < NCM; ++c) {
            bnd_s[SUB * c] = make_float2(EF, ES);
            float tt = -ES * INV_STEP;
            int idx = (int)tt;
            idx = idx < 0 ? 0 : (idx > K - 2 ? K - 2 : idx);
            float u = tt - (float)idx;
            float2 a0 = __half22float2(link_s[c * K + idx]);
            float2 a1 = __half22float2(link_s[c * K + idx + 1]);
            EF = a0.x + (a1.x - a0.x) * u;
            ES = a0.y + (a1.y - a0.y) * u;
        }
    }
    __syncthreads();
    // ---- parallel snapshot guesses ----
    {
        int c = t >> 4, j = t & 15;
        if (j > 0) {
            float ES = bnd_s[SUB * c].y;
            float tt = -ES * INV_STEP;
            int idx = (int)tt;
            idx = idx < 0 ? 0 : (idx > K - 2 ? K - 2 : idx);
            float u = tt - (float)idx;
            const __half2* m = mp + ((size_t)(b * NCM + c) * SUB + (j - 1)) * K;
            float2 a0 = __half22float2(m[idx]);
            float2 a1 = __half22float2(m[idx + 1]);
            bnd_s[t] = make_float2(a0.x + (a1.x - a0.x) * u,
                                   a0.y + (a1.y - a0.y) * u);
        }
    }
    __syncthreads();

    // ---- 3x exact Newton: jac -> wave-shfl affine scan ----
    #pragma unroll 1
    for (int it = 0; it < NIT; ++it) {
        float2 s0 = bnd_s[t];
        float EF = s0.x, ES = s0.y, Y = EF + ES;
        float jFx = 1.0f, jFy = 0.0f, jSx = 0.0f, jSy = 1.0f;

        float4 buf[DPF];
        #pragma unroll
        for (int i = 0; i < DPF; ++i) buf[i] = base4[(size_t)i * 1024 + t];

        #pragma unroll 1
        for (int vb = 0; vb < 32; vb += DPF) {
            #pragma unroll
            for (int i = 0; i < DPF; ++i) {            // static buf index
                float4 xv = buf[i];
                int nxt = vb + DPF + i;
                if (nxt < 32) buf[i] = base4[(size_t)nxt * 1024 + t];
#define SSL_STEP_J(XV) { \
                float sx2 = fmaf(nhs, (XV), hst); \
                float u2  = fmaf(nq, Y, sx2); \
                float t2  = fminf(u2, 0.0f); \
                float mm  = (u2 < 0.0f) ? nq : 0.0f; \
                bool att  = sx2 < r * Y; \
                float af  = att ? a_af : a_sf; \
                float as2 = att ? a_as : a_ss; \
                float jtx = mm * (jFx + jSx); \
                float jty = mm * (jFy + jSy); \
                jFx = fmaf(af,  jFx - jtx, jtx); \
                jFy = fmaf(af,  jFy - jty, jty); \
                jSx = fmaf(as2, jSx - jtx, jtx); \
                jSy = fmaf(as2, jSy - jty, jty); \
                EF  = fmaf(af,  EF - t2, t2); \
                ES  = fmaf(as2, ES - t2, t2); \
                Y   = EF + ES; }
                SSL_STEP_J(xv.x)
                SSL_STEP_J(xv.y)
                SSL_STEP_J(xv.z)
                SSL_STEP_J(xv.w)
#undef SSL_STEP_J
            }
        }
        float gx = EF - (jFx * s0.x + jFy * s0.y);
        float gy = ES - (jSx * s0.x + jSy * s0.y);

        // in-wave inclusive scan of affine maps (self = self ∘ prev)
        for (int d = 1; d < 64; d <<= 1) {
            float pa = __shfl_up(jFx, d), pb = __shfl_up(jFy, d);
            float pc = __shfl_up(jSx, d), pd = __shfl_up(jSy, d);
            float px = __shfl_up(gx, d),  py = __shfl_up(gy, d);
            if (lane >= d) {
                float na = jFx * pa + jFy * pc, nb = jFx * pb + jFy * pd;
                float nc = jSx * pa + jSy * pc, nd = jSx * pb + jSy * pd;
                gx = jFx * px + jFy * py + gx;
                gy = jSx * px + jSy * py + gy;
                jFx = na; jFy = nb; jSx = nc; jSy = nd;
            }
        }
        if (lane == 63) {
            aggJ[w] = make_float4(jFx, jFy, jSx, jSy);
            aggG[w] = make_float2(gx, gy);
        }
        __syncthreads();
        if (t < 16) {                                // scan 16 wave aggregates
            float4 J = aggJ[t]; float2 g = aggG[t];
            float a = J.x, bb = J.y, c = J.z, dd = J.w, ggx = g.x, ggy = g.y;
            for (int d = 1; d < 16; d <<= 1) {
                float pa = __shfl_up(a, d), pb = __shfl_up(bb, d);
                float pc = __shfl_up(c, d), pd = __shfl_up(dd, d);
                float px = __shfl_up(ggx, d), py = __shfl_up(ggy, d);
                if (t >= d) {
                    float na = a * pa + bb * pc, nb = a * pb + bb * pd;
                    float nc = c * pa + dd * pc, nd = c * pb + dd * pd;
                    ggx = a * px + bb * py + ggx;
                    ggy = c * px + dd * py + ggy;
                    a = na; bb = nb; c = nc; dd = nd;
                }
            }
            aggJ[t] = make_float4(a, bb, c, dd);
            aggG[t] = make_float2(ggx, ggy);
        }
        __syncthreads();
        float2 send;
        if (w == 0) send = make_float2(gx, gy);
        else {
            float2 pg = aggG[w - 1];
            send = make_float2(jFx * pg.x + jFy * pg.y + gx,
                               jSx * pg.x + jSy * pg.y + gy);
        }
        if (t < NC - 1) bnd_s[t + 1] = send;
        else           bnd_s[0] = make_float2(0.0f, 0.0f);
        __syncthreads();
    }

    // ---- out: exact rerun, store y ----
    {
        float2 s = bnd_s[t];
        float EF = s.x, ES = s.y, Y = EF + ES;
        float4* __restrict__ yr = reinterpret_cast<float4*>(out) + (size_t)b * NV_ROW;

        float4 buf[DPF];
        #pragma unroll
        for (int i = 0; i < DPF; ++i) buf[i] = base4[(size_t)i * 1024 + t];

        #pragma unroll 1
        for (int vb = 0; vb < 32; vb += DPF) {
            #pragma unroll
            for (int i = 0; i < DPF; ++i) {            // static buf index
                float4 xv = buf[i];
                int nxt = vb + DPF + i;
                if (nxt < 32) buf[i] = base4[(size_t)nxt * 1024 + t];
                float4 yo;
#define SSL_STEP(XV, YOUT) { \
                float sx2 = fmaf(nhs, (XV), hst); \
                float u2  = fmaf(nq, Y, sx2); \
                float t2  = fminf(u2, 0.0f); \
                bool att  = sx2 < r * Y; \
                float af  = att ? a_af : a_sf; \
                float as2 = att ? a_as : a_ss; \
                EF = fmaf(af,  EF - t2, t2); \
                ES = fmaf(as2, ES - t2, t2); \
                Y  = EF + ES; \
                (YOUT) = Y; }
                SSL_STEP(xv.x, yo.x)
                SSL_STEP(xv.y, yo.y)
                SSL_STEP(xv.z, yo.z)
                SSL_STEP(xv.w, yo.w)
#undef SSL_STEP
                yr[(size_t)t * 32 + vb + i] = yo;
            }
        }
    }
}

extern "C" void kernel_launch(void* const* d_in, const int* in_sizes, int n_in,
                              void* d_out, int out_size, void* d_ws, size_t ws_size,
                              hipStream_t stream) {
    const float* x = (const float*)d_in[0];
    const int B = in_sizes[0] / T_LEN;   // 128

    // ws layout: mp (8MB) | pw (256B) | xq (16MB) | xt (64MB)
    const size_t MP_B = (size_t)B * NCM * SUB * K * sizeof(__half2);
    const size_t PW_O = MP_B;
    const size_t XQ_O = PW_O + 256;
    const size_t XQ_B = (size_t)B * QROW * sizeof(float);
    const size_t XT_O = XQ_O + XQ_B;

    __half2* mp = (__half2*)d_ws;
    float*   pw = (float*)((char*)d_ws + PW_O);
    float*   xq = (float*)((char*)d_ws + XQ_O);
    float*   xt = (float*)((char*)d_ws + XT_O);

    ssl_params_k<<<1, 1, 0, stream>>>(
        pw,
        (const float*)d_in[1], (const float*)d_in[2], (const float*)d_in[3],
        (const float*)d_in[4], (const float*)d_in[5], (const float*)d_in[6],
        (const float*)d_in[7]);

    ssl_tr<<<2 * B, 256, 0, stream>>>(x, xt, xq);

    int map_blocks = (B * NCM * K + 255) / 256;     // 512
    ssl_map_q<<<map_blocks, 256, 0, stream>>>(xq, mp, pw, B);

    ssl_row_k<<<B, 1024, 0, stream>>>(xt, (float*)d_out, mp, pw, B);
}

// Round 17
// 162.687 us; speedup vs baseline: 1.6968x; 1.2534x over previous
//
#include <hip/hip_runtime.h>
#include <hip/hip_fp16.h>
#include <math.h>

// SSL compressor gain: 128 independent nonlinear 2-state IIR chains, T=131072.
// Round 17: split phases into kernels at their natural grid widths.
//   r16 model closure: row kernel = issue-capacity-bound at ~48% busy on HALF
//   the chip (128 row-blocks -> 128 CUs). jac/out don't need the block-local
//   scan -> run them as 512x256 over ALL 256 CUs (2x issue). guess/scan stay
//   per-row (tiny). J/g/bnd live in the dead xq region (ws stays 88MB).
//   Also fixes r16 map_q bug (consumed only half of each coarse chunk;
//   3x Newton absorbed the bad guesses - now correct, d0 ~1.3).
// Nodes: tr+params, map_q, guess, [jac, scan]x3, out = 10.

constexpr int   T_LEN    = 131072;
constexpr int   NCM      = 64;              // coarse map chunks
constexpr int   CM       = T_LEN / NCM;     // 2048 samples
constexpr int   SUB      = 16;              // snapshots per map chunk (every 128)
constexpr int   NC       = NCM * SUB;       // 1024 fine chunks
constexpr int   CF       = T_LEN / NC;      // 128 samples
constexpr int   K        = 16;              // ES nodes: 0 .. -8, h=8/15
constexpr float STEP_ES  = 8.0f / 15.0f;
constexpr float INV_STEP = 15.0f / 8.0f;
constexpr int   DPF      = 8;
constexpr int   NV_ROW   = T_LEN >> 2;      // 32768 float4 per row
constexpr int   QROW     = T_LEN >> 2;      // 32768 quad sums per row
constexpr int   NIT      = 3;               // exact Newton iterations
constexpr int   LINK     = NCM * K;         // 1024

// pw: 0 nhs, 1 hst, 2 nq, 3 r, 4..7 a_{af,as,sf,ss}, 8..11 a^4, 12 nhs_q
__device__ void compute_params(
        float* __restrict__ pw,
        const float* cth, const float* rl, const float* fbl,
        const float* uaf, const float* uas, const float* usf, const float* uss)
{
    const double FS = 44100.0;
    const double T_AF_MIN = 820.0 * 4.7e-07 * 0.8,   T_AF_MAX = 270000.0 * 4.7e-07 * 1.2;
    const double T_AS_MIN = 820.0 * 6.8e-06 * 0.8,   T_AS_MAX = 270000.0 * 6.8e-06 * 100.0;
    const double T_SF_MIN = 91000.0 * 4.7e-07 * 0.8, T_SF_MAX = 1200000.0 * 4.7e-07 * 1.2;
    const double T_SS_MIN = 750000.0 * 6.8e-06 * 0.8, T_SS_MAX = 750000.0 * 6.8e-06 * 100.0;

    double cr    = fmax(exp((double)rl[0]) + 1.0, 1.0 + 1e-4);
    double fb    = 1.0 / (1.0 + exp(-(double)fbl[0]));
    double slope = 1.0 - 1.0 / cr;

    double s_af = T_AF_MIN + (T_AF_MAX - T_AF_MIN) / (1.0 + exp(-(double)uaf[0]));
    double s_as = T_AS_MIN + (T_AS_MAX - T_AS_MIN) / (1.0 + exp(-(double)uas[0]));
    double s_sf = T_SF_MIN + (T_SF_MAX - T_SF_MIN) / (1.0 + exp(-(double)usf[0]));
    double s_ss = T_SS_MIN + (T_SS_MAX - T_SS_MIN) / (1.0 + exp(-(double)uss[0]));

    float a_af = (float)exp(-1.0 / (FS * s_af));
    float a_as = (float)exp(-1.0 / (FS * s_as));
    float a_sf = (float)exp(-1.0 / (FS * s_sf));
    float a_ss = (float)exp(-1.0 / (FS * s_ss));
    double q = 0.5 * slope * fb;

    pw[0]  = (float)(-0.5 * slope);
    pw[1]  = (float)(0.5 * slope * (double)cth[0]);
    pw[2]  = (float)(-q);
    pw[3]  = (float)(0.5 + q);
    pw[4]  = a_af;  pw[5] = a_as;  pw[6] = a_sf;  pw[7] = a_ss;
    float e_af = a_af * a_af, e_as = a_as * a_as, e_sf = a_sf * a_sf, e_ss = a_ss * a_ss;
    pw[8]  = e_af * e_af;  pw[9]  = e_as * e_as;   // a^4
    pw[10] = e_sf * e_sf;  pw[11] = e_ss * e_ss;
    pw[12] = (float)(-0.125 * slope);              // quad-avg input coef
}

// Corner-turn x -> x_t[b][blk][chunk] + quad sums xq; block 0 also computes pw.
__global__ __launch_bounds__(256) void ssl_tr(
        const float* __restrict__ x, float* __restrict__ xt,
        float* __restrict__ xq, float* __restrict__ pw,
        const float* cth, const float* rl, const float* fbl,
        const float* uaf, const float* uas, const float* usf, const float* uss)
{
    if (blockIdx.x == 0 && threadIdx.x == 0)
        compute_params(pw, cth, rl, fbl, uaf, uas, usf, uss);

    __shared__ float lds[64][129];
    const int b = blockIdx.x >> 1;
    const int h = blockIdx.x & 1;
    const int tid = threadIdx.x;
    const float4* __restrict__ x4 = reinterpret_cast<const float4*>(x) + (size_t)b * NV_ROW;
    float4* __restrict__ xt4      = reinterpret_cast<float4*>(xt) + (size_t)b * NV_ROW;
    float* __restrict__ xqr       = xq + (size_t)b * QROW;

    for (int tile = h * 8; tile < h * 8 + 8; ++tile) {
        const int c0 = tile * 64;                      // 64 fine chunks per tile
        #pragma unroll
        for (int it = 0; it < 8; ++it) {
            int idx = it * 256 + tid;                  // 0..2047 float4
            int c = idx >> 5, s4 = idx & 31;
            float4 v = x4[(size_t)(c0 + c) * 32 + s4];
            lds[c][s4 * 4 + 0] = v.x; lds[c][s4 * 4 + 1] = v.y;
            lds[c][s4 * 4 + 2] = v.z; lds[c][s4 * 4 + 3] = v.w;
        }
        __syncthreads();
        #pragma unroll
        for (int it = 0; it < 8; ++it) {
            int idx = it * 256 + tid;
            int blk = idx >> 6, c = idx & 63;
            float4 w;
            w.x = lds[c][blk * 4 + 0]; w.y = lds[c][blk * 4 + 1];
            w.z = lds[c][blk * 4 + 2]; w.w = lds[c][blk * 4 + 3];
            xt4[(size_t)blk * 1024 + c0 + c] = w;
        }
        #pragma unroll
        for (int it = 0; it < 8; ++it) {
            int qi = it * 256 + tid;
            int cc = qi >> 5, off = (qi & 31) * 4;
            float s = (lds[cc][off] + lds[cc][off + 1]) + (lds[cc][off + 2] + lds[cc][off + 3]);
            xqr[c0 * 32 + qi] = s;
        }
        __syncthreads();
    }
}

// 4x-decimated diagonal chunk maps at K ES-nodes; SUB snapshots per chunk.
// FIXED vs r16: consume all 128 float4 per coarse chunk, snapshot every 8.
__global__ __launch_bounds__(256) void ssl_map_q(
        const float* __restrict__ xq, __half2* __restrict__ mp,
        const float* __restrict__ pw, int B)
{
    int tid = blockIdx.x * 256 + threadIdx.x;
    int k  = tid & (K - 1);
    int bc = tid >> 4;
    if (bc >= B * NCM) return;
    int c  = bc & (NCM - 1);
    int b  = bc >> 6;

    const float nhs_q = pw[12], hst = pw[1], nq = pw[2], r = pw[3];
    const float e_af = pw[8], e_as = pw[9], e_sf = pw[10], e_ss = pw[11];

    float v0s = -STEP_ES * (float)k;
    float EF = v0s, ES = v0s, Y = EF + ES;
    const float4* __restrict__ q4 =
        reinterpret_cast<const float4*>(xq) + (size_t)b * (QROW >> 2) + (size_t)c * (CM >> 4);

    float4 buf[DPF];
    #pragma unroll
    for (int i = 0; i < DPF; ++i) buf[i] = q4[i];

    #pragma unroll 1
    for (int s = 0; s < SUB; ++s) {                   // 8 float4 = 128 samples
        #pragma unroll
        for (int i = 0; i < DPF; ++i) {
            float4 xv = buf[i];
            int nxt = s * DPF + DPF + i;
            if (nxt < (CM >> 4)) buf[i] = q4[nxt];
#define QSTEP(XS) { \
            float sx2 = fmaf(nhs_q, (XS), hst); \
            float u2  = fmaf(nq, Y, sx2); \
            float t2  = fminf(u2, 0.0f); \
            bool att  = sx2 < r * Y; \
            float af  = att ? e_af : e_sf; \
            float as2 = att ? e_as : e_ss; \
            EF = fmaf(af,  EF - t2, t2); \
            ES = fmaf(as2, ES - t2, t2); \
            Y  = EF + ES; }
            QSTEP(xv.x) QSTEP(xv.y) QSTEP(xv.z) QSTEP(xv.w)
#undef QSTEP
        }
        mp[((size_t)bc * SUB + s) * K + k] = __floats2half2_rn(EF, ES);
    }
}

// Per-row: link-stage -> serial compose0 -> snapshot guesses -> bnd (global).
__global__ __launch_bounds__(1024) void ssl_guess(
        const __half2* __restrict__ mp, float2* __restrict__ bnd,
        const float* __restrict__ pw, int B)
{
    __shared__ __half2 link_s[LINK];
    __shared__ float2 bnd_s[NC];
    const int b = blockIdx.x;
    const int t = threadIdx.x;

    {
        int c = t >> 4, k = t & 15;
        link_s[t] = mp[((size_t)(b * NCM + c) * SUB + (SUB - 1)) * K + k];
    }
    __syncthreads();

    if (t == 0) {
        float EF = 0.0f, ES = 0.0f;
        for (int c = 0; c < NCM; ++c) {
            bnd_s[SUB * c] = make_float2(EF, ES);
            float tt = -ES * INV_STEP;
            int idx = (int)tt;
            idx = idx < 0 ? 0 : (idx > K - 2 ? K - 2 : idx);
            float u = tt - (float)idx;
            float2 a0 = __half22float2(link_s[c * K + idx]);
            float2 a1 = __half22float2(link_s[c * K + idx + 1]);
            EF = a0.x + (a1.x - a0.x) * u;
            ES = a0.y + (a1.y - a0.y) * u;
        }
    }
    __syncthreads();
    {
        int c = t >> 4, j = t & 15;
        if (j > 0) {
            float ES = bnd_s[SUB * c].y;
            float tt = -ES * INV_STEP;
            int idx = (int)tt;
            idx = idx < 0 ? 0 : (idx > K - 2 ? K - 2 : idx);
            float u = tt - (float)idx;
            const __half2* m = mp + ((size_t)(b * NCM + c) * SUB + (j - 1)) * K;
            float2 a0 = __half22float2(m[idx]);
            float2 a1 = __half22float2(m[idx + 1]);
            bnd_s[t] = make_float2(a0.x + (a1.x - a0.x) * u,
                                   a0.y + (a1.y - a0.y) * u);
        }
    }
    __syncthreads();
    bnd[(size_t)b * NC + t] = bnd_s[t];
}

// Full-grid jac: 512 blocks x 256 thr (all CUs). block -> (row, 256 chunks).
__global__ __launch_bounds__(256) void ssl_jac_g(
        const float* __restrict__ xt, const float2* __restrict__ bnd,
        float4* __restrict__ Jv, float2* __restrict__ gv,
        const float* __restrict__ pw)
{
    const int b = blockIdx.x >> 2;
    const int c = ((blockIdx.x & 3) << 8) | threadIdx.x;

    const float nhs = pw[0], hst = pw[1], nq = pw[2], r = pw[3];
    const float a_af = pw[4], a_as = pw[5], a_sf = pw[6], a_ss = pw[7];

    const float4* __restrict__ base4 =
        reinterpret_cast<const float4*>(xt) + (size_t)b * NV_ROW;

    float2 s0 = bnd[(size_t)b * NC + c];
    float EF = s0.x, ES = s0.y, Y = EF + ES;
    float jFx = 1.0f, jFy = 0.0f, jSx = 0.0f, jSy = 1.0f;

    float4 buf[DPF];
    #pragma unroll
    for (int i = 0; i < DPF; ++i) buf[i] = base4[(size_t)i * 1024 + c];

    #pragma unroll 1
    for (int vb = 0; vb < 32; vb += DPF) {
        #pragma unroll
        for (int i = 0; i < DPF; ++i) {                // static buf index
            float4 xv = buf[i];
            int nxt = vb + DPF + i;
            if (nxt < 32) buf[i] = base4[(size_t)nxt * 1024 + c];
#define SSL_STEP_J(XV) { \
            float sx2 = fmaf(nhs, (XV), hst); \
            float u2  = fmaf(nq, Y, sx2); \
            float t2  = fminf(u2, 0.0f); \
            float mm  = (u2 < 0.0f) ? nq : 0.0f; \
            bool att  = sx2 < r * Y; \
            float af  = att ? a_af : a_sf; \
            float as2 = att ? a_as : a_ss; \
            float jtx = mm * (jFx + jSx); \
            float jty = mm * (jFy + jSy); \
            jFx = fmaf(af,  jFx - jtx, jtx); \
            jFy = fmaf(af,  jFy - jty, jty); \
            jSx = fmaf(as2, jSx - jtx, jtx); \
            jSy = fmaf(as2, jSy - jty, jty); \
            EF  = fmaf(af,  EF - t2, t2); \
            ES  = fmaf(as2, ES - t2, t2); \
            Y   = EF + ES; }
            SSL_STEP_J(xv.x)
            SSL_STEP_J(xv.y)
            SSL_STEP_J(xv.z)
            SSL_STEP_J(xv.w)
#undef SSL_STEP_J
        }
    }
    Jv[(size_t)b * NC + c] = make_float4(jFx, jFy, jSx, jSy);
    gv[(size_t)b * NC + c] = make_float2(EF - (jFx * s0.x + jFy * s0.y),
                                         ES - (jSx * s0.x + jSy * s0.y));
}

// Per-row wave-shfl affine scan: bnd[c] = state before chunk c.
__global__ __launch_bounds__(1024) void ssl_scan_g(
        const float4* __restrict__ Jv, const float2* __restrict__ gv,
        float2* __restrict__ bnd)
{
    __shared__ float4 aggJ[16];
    __shared__ float2 aggG[16];
    const int b = blockIdx.x;
    const int t = threadIdx.x;
    const int lane = t & 63, w = t >> 6;

    float4 J = Jv[(size_t)b * NC + t];
    float2 g = gv[(size_t)b * NC + t];
    float jFx = J.x, jFy = J.y, jSx = J.z, jSy = J.w, gx = g.x, gy = g.y;

    for (int d = 1; d < 64; d <<= 1) {
        float pa = __shfl_up(jFx, d), pb = __shfl_up(jFy, d);
        float pc = __shfl_up(jSx, d), pd = __shfl_up(jSy, d);
        float px = __shfl_up(gx, d),  py = __shfl_up(gy, d);
        if (lane >= d) {
            float na = jFx * pa + jFy * pc, nb = jFx * pb + jFy * pd;
            float nc = jSx * pa + jSy * pc, nd = jSx * pb + jSy * pd;
            gx = jFx * px + jFy * py + gx;
            gy = jSx * px + jSy * py + gy;
            jFx = na; jFy = nb; jSx = nc; jSy = nd;
        }
    }
    if (lane == 63) {
        aggJ[w] = make_float4(jFx, jFy, jSx, jSy);
        aggG[w] = make_float2(gx, gy);
    }
    __syncthreads();
    if (t < 16) {
        float4 Ja = aggJ[t]; float2 ga = aggG[t];
        float a = Ja.x, bb = Ja.y, c = Ja.z, dd = Ja.w, ggx = ga.x, ggy = ga.y;
        for (int d = 1; d < 16; d <<= 1) {
            float pa = __shfl_up(a, d), pb = __shfl_up(bb, d);
            float pc = __shfl_up(c, d), pd = __shfl_up(dd, d);
            float px = __shfl_up(ggx, d), py = __shfl_up(ggy, d);
            if (t >= d) {
                float na = a * pa + bb * pc, nb = a * pb + bb * pd;
                float nc = c * pa + dd * pc, nd = c * pb + dd * pd;
                ggx = a * px + bb * py + ggx;
                ggy = c * px + dd * py + ggy;
                a = na; bb = nb; c = nc; dd = nd;
            }
        }
        aggJ[t] = make_float4(a, bb, c, dd);
        aggG[t] = make_float2(ggx, ggy);
    }
    __syncthreads();
    float2 send;
    if (w == 0) send = make_float2(gx, gy);
    else {
        float2 pg = aggG[w - 1];
        send = make_float2(jFx * pg.x + jFy * pg.y + gx,
                           jSx * pg.x + jSy * pg.y + gy);
    }
    if (t < NC - 1) bnd[(size_t)b * NC + t + 1] = send;
    else            bnd[(size_t)b * NC] = make_float2(0.0f, 0.0f);
}

// Full-grid out: exact rerun from corrected states, store y.
__global__ __launch_bounds__(256) void ssl_out_g(
        const float* __restrict__ xt, float* __restrict__ out,
        const float2* __restrict__ bnd, const float* __restrict__ pw)
{
    const int b = blockIdx.x >> 2;
    const int c = ((blockIdx.x & 3) << 8) | threadIdx.x;

    const float nhs = pw[0], hst = pw[1], nq = pw[2], r = pw[3];
    const float a_af = pw[4], a_as = pw[5], a_sf = pw[6], a_ss = pw[7];

    const float4* __restrict__ base4 =
        reinterpret_cast<const float4*>(xt) + (size_t)b * NV_ROW;
    float4* __restrict__ yr = reinterpret_cast<float4*>(out) + (size_t)b * NV_ROW;

    float2 s = bnd[(size_t)b * NC + c];
    float EF = s.x, ES = s.y, Y = EF + ES;

    float4 buf[DPF];
    #pragma unroll
    for (int i = 0; i < DPF; ++i) buf[i] = base4[(size_t)i * 1024 + c];

    #pragma unroll 1
    for (int vb = 0; vb < 32; vb += DPF) {
        #pragma unroll
        for (int i = 0; i < DPF; ++i) {                // static buf index
            float4 xv = buf[i];
            int nxt = vb + DPF + i;
            if (nxt < 32) buf[i] = base4[(size_t)nxt * 1024 + c];
            float4 yo;
#define SSL_STEP(XV, YOUT) { \
            float sx2 = fmaf(nhs, (XV), hst); \
            float u2  = fmaf(nq, Y, sx2); \
            float t2  = fminf(u2, 0.0f); \
            bool att  = sx2 < r * Y; \
            float af  = att ? a_af : a_sf; \
            float as2 = att ? a_as : a_ss; \
            EF = fmaf(af,  EF - t2, t2); \
            ES = fmaf(as2, ES - t2, t2); \
            Y  = EF + ES; \
            (YOUT) = Y; }
            SSL_STEP(xv.x, yo.x)
            SSL_STEP(xv.y, yo.y)
            SSL_STEP(xv.z, yo.z)
            SSL_STEP(xv.w, yo.w)
#undef SSL_STEP
            yr[(size_t)c * 32 + vb + i] = yo;
        }
    }
}

extern "C" void kernel_launch(void* const* d_in, const int* in_sizes, int n_in,
                              void* d_out, int out_size, void* d_ws, size_t ws_size,
                              hipStream_t stream) {
    const float* x = (const float*)d_in[0];
    const int B = in_sizes[0] / T_LEN;   // 128

    // ws: mp 8MB | pw 256B | xq 16MB (reused after map as bnd/Jv/gv) | xt 64MB
    const size_t MP_B = (size_t)B * NCM * SUB * K * sizeof(__half2);
    const size_t PW_O = MP_B;
    const size_t XQ_O = PW_O + 256;
    const size_t XQ_B = (size_t)B * QROW * sizeof(float);
    const size_t XT_O = XQ_O + XQ_B;

    __half2* mp  = (__half2*)d_ws;
    float*   pw  = (float*)((char*)d_ws + PW_O);
    float*   xq  = (float*)((char*)d_ws + XQ_O);
    float*   xt  = (float*)((char*)d_ws + XT_O);
    // xq region reuse (xq dead after ssl_map_q):
    float2*  bnd = (float2*)xq;                             // 1 MB
    float4*  Jv  = (float4*)((char*)xq + (1u << 20));       // 2 MB
    float2*  gv  = (float2*)((char*)xq + (3u << 20));       // 1 MB

    ssl_tr<<<2 * B, 256, 0, stream>>>(
        x, xt, xq, pw,
        (const float*)d_in[1], (const float*)d_in[2], (const float*)d_in[3],
        (const float*)d_in[4], (const float*)d_in[5], (const float*)d_in[6],
        (const float*)d_in[7]);

    int map_blocks = (B * NCM * K + 255) / 256;     // 512
    ssl_map_q<<<map_blocks, 256, 0, stream>>>(xq, mp, pw, B);

    ssl_guess<<<B, 1024, 0, stream>>>(mp, bnd, pw, B);

    for (int it = 0; it < NIT; ++it) {
        ssl_jac_g<<<4 * B, 256, 0, stream>>>(xt, bnd, Jv, gv, pw);
        ssl_scan_g<<<B, 1024, 0, stream>>>(Jv, gv, bnd);
    }

    ssl_out_g<<<4 * B, 256, 0, stream>>>(xt, (float*)d_out, bnd, pw);
}

// Round 18
// 156.020 us; speedup vs baseline: 1.7694x; 1.0427x over previous
//
#include <hip/hip_runtime.h>
#include <hip/hip_fp16.h>
#include <math.h>

// SSL compressor gain: 128 independent nonlinear 2-state IIR chains, T=131072.
// Round 18: r17 with the transpose kernel fixed.
//   r17 post-mortem: ssl_tr = 64us with 3.1M LDS bank conflicts (scalar f32
//   LDS ops, 4-way write conflicts) and 9.5% occupancy (1 block/CU, 2
//   barriers x 16 tiles serialized). Fix: float4 LDS both sides on a
//   [64][33]-float4 padded tile (canonical conflict-free transpose), quad-sum
//   fused into the load phase (each loaded float4 IS one xq quad), one tile
//   per block (2048 blocks -> 4 blocks/CU, 16 waves/CU, 1 barrier).
//   All other kernels bit-identical to r17 (162us, absmax 0.125).

constexpr int   T_LEN    = 131072;
constexpr int   NCM      = 64;              // coarse map chunks
constexpr int   CM       = T_LEN / NCM;     // 2048 samples
constexpr int   SUB      = 16;              // snapshots per map chunk (every 128)
constexpr int   NC       = NCM * SUB;       // 1024 fine chunks
constexpr int   CF       = T_LEN / NC;      // 128 samples
constexpr int   K        = 16;              // ES nodes: 0 .. -8, h=8/15
constexpr float STEP_ES  = 8.0f / 15.0f;
constexpr float INV_STEP = 15.0f / 8.0f;
constexpr int   DPF      = 8;
constexpr int   NV_ROW   = T_LEN >> 2;      // 32768 float4 per row
constexpr int   QROW     = T_LEN >> 2;      // 32768 quad sums per row
constexpr int   NIT      = 3;               // exact Newton iterations
constexpr int   LINK     = NCM * K;         // 1024

// pw: 0 nhs, 1 hst, 2 nq, 3 r, 4..7 a_{af,as,sf,ss}, 8..11 a^4, 12 nhs_q
__device__ void compute_params(
        float* __restrict__ pw,
        const float* cth, const float* rl, const float* fbl,
        const float* uaf, const float* uas, const float* usf, const float* uss)
{
    const double FS = 44100.0;
    const double T_AF_MIN = 820.0 * 4.7e-07 * 0.8,   T_AF_MAX = 270000.0 * 4.7e-07 * 1.2;
    const double T_AS_MIN = 820.0 * 6.8e-06 * 0.8,   T_AS_MAX = 270000.0 * 6.8e-06 * 100.0;
    const double T_SF_MIN = 91000.0 * 4.7e-07 * 0.8, T_SF_MAX = 1200000.0 * 4.7e-07 * 1.2;
    const double T_SS_MIN = 750000.0 * 6.8e-06 * 0.8, T_SS_MAX = 750000.0 * 6.8e-06 * 100.0;

    double cr    = fmax(exp((double)rl[0]) + 1.0, 1.0 + 1e-4);
    double fb    = 1.0 / (1.0 + exp(-(double)fbl[0]));
    double slope = 1.0 - 1.0 / cr;

    double s_af = T_AF_MIN + (T_AF_MAX - T_AF_MIN) / (1.0 + exp(-(double)uaf[0]));
    double s_as = T_AS_MIN + (T_AS_MAX - T_AS_MIN) / (1.0 + exp(-(double)uas[0]));
    double s_sf = T_SF_MIN + (T_SF_MAX - T_SF_MIN) / (1.0 + exp(-(double)usf[0]));
    double s_ss = T_SS_MIN + (T_SS_MAX - T_SS_MIN) / (1.0 + exp(-(double)uss[0]));

    float a_af = (float)exp(-1.0 / (FS * s_af));
    float a_as = (float)exp(-1.0 / (FS * s_as));
    float a_sf = (float)exp(-1.0 / (FS * s_sf));
    float a_ss = (float)exp(-1.0 / (FS * s_ss));
    double q = 0.5 * slope * fb;

    pw[0]  = (float)(-0.5 * slope);
    pw[1]  = (float)(0.5 * slope * (double)cth[0]);
    pw[2]  = (float)(-q);
    pw[3]  = (float)(0.5 + q);
    pw[4]  = a_af;  pw[5] = a_as;  pw[6] = a_sf;  pw[7] = a_ss;
    float e_af = a_af * a_af, e_as = a_as * a_as, e_sf = a_sf * a_sf, e_ss = a_ss * a_ss;
    pw[8]  = e_af * e_af;  pw[9]  = e_as * e_as;   // a^4
    pw[10] = e_sf * e_sf;  pw[11] = e_ss * e_ss;
    pw[12] = (float)(-0.125 * slope);              // quad-avg input coef
}

// Corner-turn x -> x_t[b][blk][chunk] + quad sums xq (fused into load phase).
// 2048 blocks (16/row), one 64-chunk tile each; float4 LDS ops, [64][33] pad.
__global__ __launch_bounds__(256) void ssl_tr(
        const float* __restrict__ x, float* __restrict__ xt,
        float* __restrict__ xq, float* __restrict__ pw,
        const float* cth, const float* rl, const float* fbl,
        const float* uaf, const float* uas, const float* usf, const float* uss)
{
    if (blockIdx.x == 0 && threadIdx.x == 0)
        compute_params(pw, cth, rl, fbl, uaf, uas, usf, uss);

    __shared__ float4 lds4[64][33];                    // 33 KB, +1 f4 pad
    const int b    = blockIdx.x >> 4;
    const int tile = blockIdx.x & 15;
    const int tid  = threadIdx.x;
    const int c0   = tile * 64;                        // first fine chunk

    const float4* __restrict__ x4 = reinterpret_cast<const float4*>(x) + (size_t)b * NV_ROW;
    float4* __restrict__ xt4      = reinterpret_cast<float4*>(xt) + (size_t)b * NV_ROW;
    float* __restrict__ xqr       = xq + (size_t)b * QROW;

    #pragma unroll
    for (int it = 0; it < 8; ++it) {                   // load + quad sums
        int idx = it * 256 + tid;                      // 0..2047
        int c = idx >> 5, s4 = idx & 31;
        float4 v = x4[(size_t)(c0 + c) * 32 + s4];
        lds4[c][s4] = v;
        xqr[(size_t)(c0 + c) * 32 + s4] = (v.x + v.y) + (v.z + v.w);
    }
    __syncthreads();
    #pragma unroll
    for (int it = 0; it < 8; ++it) {                   // transposed store
        int idx = it * 256 + tid;
        int blk = idx >> 6, c = idx & 63;
        xt4[(size_t)blk * 1024 + c0 + c] = lds4[c][blk];
    }
}

// 4x-decimated diagonal chunk maps at K ES-nodes; SUB snapshots per chunk.
__global__ __launch_bounds__(256) void ssl_map_q(
        const float* __restrict__ xq, __half2* __restrict__ mp,
        const float* __restrict__ pw, int B)
{
    int tid = blockIdx.x * 256 + threadIdx.x;
    int k  = tid & (K - 1);
    int bc = tid >> 4;
    if (bc >= B * NCM) return;
    int c  = bc & (NCM - 1);
    int b  = bc >> 6;

    const float nhs_q = pw[12], hst = pw[1], nq = pw[2], r = pw[3];
    const float e_af = pw[8], e_as = pw[9], e_sf = pw[10], e_ss = pw[11];

    float v0s = -STEP_ES * (float)k;
    float EF = v0s, ES = v0s, Y = EF + ES;
    const float4* __restrict__ q4 =
        reinterpret_cast<const float4*>(xq) + (size_t)b * (QROW >> 2) + (size_t)c * (CM >> 4);

    float4 buf[DPF];
    #pragma unroll
    for (int i = 0; i < DPF; ++i) buf[i] = q4[i];

    #pragma unroll 1
    for (int s = 0; s < SUB; ++s) {                   // 8 float4 = 128 samples
        #pragma unroll
        for (int i = 0; i < DPF; ++i) {
            float4 xv = buf[i];
            int nxt = s * DPF + DPF + i;
            if (nxt < (CM >> 4)) buf[i] = q4[nxt];
#define QSTEP(XS) { \
            float sx2 = fmaf(nhs_q, (XS), hst); \
            float u2  = fmaf(nq, Y, sx2); \
            float t2  = fminf(u2, 0.0f); \
            bool att  = sx2 < r * Y; \
            float af  = att ? e_af : e_sf; \
            float as2 = att ? e_as : e_ss; \
            EF = fmaf(af,  EF - t2, t2); \
            ES = fmaf(as2, ES - t2, t2); \
            Y  = EF + ES; }
            QSTEP(xv.x) QSTEP(xv.y) QSTEP(xv.z) QSTEP(xv.w)
#undef QSTEP
        }
        mp[((size_t)bc * SUB + s) * K + k] = __floats2half2_rn(EF, ES);
    }
}

// Per-row: link-stage -> serial compose0 -> snapshot guesses -> bnd (global).
__global__ __launch_bounds__(1024) void ssl_guess(
        const __half2* __restrict__ mp, float2* __restrict__ bnd,
        const float* __restrict__ pw, int B)
{
    __shared__ __half2 link_s[LINK];
    __shared__ float2 bnd_s[NC];
    const int b = blockIdx.x;
    const int t = threadIdx.x;

    {
        int c = t >> 4, k = t & 15;
        link_s[t] = mp[((size_t)(b * NCM + c) * SUB + (SUB - 1)) * K + k];
    }
    __syncthreads();

    if (t == 0) {
        float EF = 0.0f, ES = 0.0f;
        for (int c = 0; c < NCM; ++c) {
            bnd_s[SUB * c] = make_float2(EF, ES);
            float tt = -ES * INV_STEP;
            int idx = (int)tt;
            idx = idx < 0 ? 0 : (idx > K - 2 ? K - 2 : idx);
            float u = tt - (float)idx;
            float2 a0 = __half22float2(link_s[c * K + idx]);
            float2 a1 = __half22float2(link_s[c * K + idx + 1]);
            EF = a0.x + (a1.x - a0.x) * u;
            ES = a0.y + (a1.y - a0.y) * u;
        }
    }
    __syncthreads();
    {
        int c = t >> 4, j = t & 15;
        if (j > 0) {
            float ES = bnd_s[SUB * c].y;
            float tt = -ES * INV_STEP;
            int idx = (int)tt;
            idx = idx < 0 ? 0 : (idx > K - 2 ? K - 2 : idx);
            float u = tt - (float)idx;
            const __half2* m = mp + ((size_t)(b * NCM + c) * SUB + (j - 1)) * K;
            float2 a0 = __half22float2(m[idx]);
            float2 a1 = __half22float2(m[idx + 1]);
            bnd_s[t] = make_float2(a0.x + (a1.x - a0.x) * u,
                                   a0.y + (a1.y - a0.y) * u);
        }
    }
    __syncthreads();
    bnd[(size_t)b * NC + t] = bnd_s[t];
}

// Full-grid jac: 512 blocks x 256 thr (all CUs). block -> (row, 256 chunks).
__global__ __launch_bounds__(256) void ssl_jac_g(
        const float* __restrict__ xt, const float2* __restrict__ bnd,
        float4* __restrict__ Jv, float2* __restrict__ gv,
        const float* __restrict__ pw)
{
    const int b = blockIdx.x >> 2;
    const int c = ((blockIdx.x & 3) << 8) | threadIdx.x;

    const float nhs = pw[0], hst = pw[1], nq = pw[2], r = pw[3];
    const float a_af = pw[4], a_as = pw[5], a_sf = pw[6], a_ss = pw[7];

    const float4* __restrict__ base4 =
        reinterpret_cast<const float4*>(xt) + (size_t)b * NV_ROW;

    float2 s0 = bnd[(size_t)b * NC + c];
    float EF = s0.x, ES = s0.y, Y = EF + ES;
    float jFx = 1.0f, jFy = 0.0f, jSx = 0.0f, jSy = 1.0f;

    float4 buf[DPF];
    #pragma unroll
    for (int i = 0; i < DPF; ++i) buf[i] = base4[(size_t)i * 1024 + c];

    #pragma unroll 1
    for (int vb = 0; vb < 32; vb += DPF) {
        #pragma unroll
        for (int i = 0; i < DPF; ++i) {                // static buf index
            float4 xv = buf[i];
            int nxt = vb + DPF + i;
            if (nxt < 32) buf[i] = base4[(size_t)nxt * 1024 + c];
#define SSL_STEP_J(XV) { \
            float sx2 = fmaf(nhs, (XV), hst); \
            float u2  = fmaf(nq, Y, sx2); \
            float t2  = fminf(u2, 0.0f); \
            float mm  = (u2 < 0.0f) ? nq : 0.0f; \
            bool att  = sx2 < r * Y; \
            float af  = att ? a_af : a_sf; \
            float as2 = att ? a_as : a_ss; \
            float jtx = mm * (jFx + jSx); \
            float jty = mm * (jFy + jSy); \
            jFx = fmaf(af,  jFx - jtx, jtx); \
            jFy = fmaf(af,  jFy - jty, jty); \
            jSx = fmaf(as2, jSx - jtx, jtx); \
            jSy = fmaf(as2, jSy - jty, jty); \
            EF  = fmaf(af,  EF - t2, t2); \
            ES  = fmaf(as2, ES - t2, t2); \
            Y   = EF + ES; }
            SSL_STEP_J(xv.x)
            SSL_STEP_J(xv.y)
            SSL_STEP_J(xv.z)
            SSL_STEP_J(xv.w)
#undef SSL_STEP_J
        }
    }
    Jv[(size_t)b * NC + c] = make_float4(jFx, jFy, jSx, jSy);
    gv[(size_t)b * NC + c] = make_float2(EF - (jFx * s0.x + jFy * s0.y),
                                         ES - (jSx * s0.x + jSy * s0.y));
}

// Per-row wave-shfl affine scan: bnd[c] = state before chunk c.
__global__ __launch_bounds__(1024) void ssl_scan_g(
        const float4* __restrict__ Jv, const float2* __restrict__ gv,
        float2* __restrict__ bnd)
{
    __shared__ float4 aggJ[16];
    __shared__ float2 aggG[16];
    const int b = blockIdx.x;
    const int t = threadIdx.x;
    const int lane = t & 63, w = t >> 6;

    float4 J = Jv[(size_t)b * NC + t];
    float2 g = gv[(size_t)b * NC + t];
    float jFx = J.x, jFy = J.y, jSx = J.z, jSy = J.w, gx = g.x, gy = g.y;

    for (int d = 1; d < 64; d <<= 1) {
        float pa = __shfl_up(jFx, d), pb = __shfl_up(jFy, d);
        float pc = __shfl_up(jSx, d), pd = __shfl_up(jSy, d);
        float px = __shfl_up(gx, d),  py = __shfl_up(gy, d);
        if (lane >= d) {
            float na = jFx * pa + jFy * pc, nb = jFx * pb + jFy * pd;
            float nc = jSx * pa + jSy * pc, nd = jSx * pb + jSy * pd;
            gx = jFx * px + jFy * py + gx;
            gy = jSx * px + jSy * py + gy;
            jFx = na; jFy = nb; jSx = nc; jSy = nd;
        }
    }
    if (lane == 63) {
        aggJ[w] = make_float4(jFx, jFy, jSx, jSy);
        aggG[w] = make_float2(gx, gy);
    }
    __syncthreads();
    if (t < 16) {
        float4 Ja = aggJ[t]; float2 ga = aggG[t];
        float a = Ja.x, bb = Ja.y, c = Ja.z, dd = Ja.w, ggx = ga.x, ggy = ga.y;
        for (int d = 1; d < 16; d <<= 1) {
            float pa = __shfl_up(a, d), pb = __shfl_up(bb, d);
            float pc = __shfl_up(c, d), pd = __shfl_up(dd, d);
            float px = __shfl_up(ggx, d), py = __shfl_up(ggy, d);
            if (t >= d) {
                float na = a * pa + bb * pc, nb = a * pb + bb * pd;
                float nc = c * pa + dd * pc, nd = c * pb + dd * pd;
                ggx = a * px + bb * py + ggx;
                ggy = c * px + dd * py + ggy;
                a = na; bb = nb; c = nc; dd = nd;
            }
        }
        aggJ[t] = make_float4(a, bb, c, dd);
        aggG[t] = make_float2(ggx, ggy);
    }
    __syncthreads();
    float2 send;
    if (w == 0) send = make_float2(gx, gy);
    else {
        float2 pg = aggG[w - 1];
        send = make_float2(jFx * pg.x + jFy * pg.y + gx,
                           jSx * pg.x + jSy * pg.y + gy);
    }
    if (t < NC - 1) bnd[(size_t)b * NC + t + 1] = send;
    else            bnd[(size_t)b * NC] = make_float2(0.0f, 0.0f);
}

// Full-grid out: exact rerun from corrected states, store y.
__global__ __launch_bounds__(256) void ssl_out_g(
        const float* __restrict__ xt, float* __restrict__ out,
        const float2* __restrict__ bnd, const float* __restrict__ pw)
{
    const int b = blockIdx.x >> 2;
    const int c = ((blockIdx.x & 3) << 8) | threadIdx.x;

    const float nhs = pw[0], hst = pw[1], nq = pw[2], r = pw[3];
    const float a_af = pw[4], a_as = pw[5], a_sf = pw[6], a_ss = pw[7];

    const float4* __restrict__ base4 =
        reinterpret_cast<const float4*>(xt) + (size_t)b * NV_ROW;
    float4* __restrict__ yr = reinterpret_cast<float4*>(out) + (size_t)b * NV_ROW;

    float2 s = bnd[(size_t)b * NC + c];
    float EF = s.x, ES = s.y, Y = EF + ES;

    float4 buf[DPF];
    #pragma unroll
    for (int i = 0; i < DPF; ++i) buf[i] = base4[(size_t)i * 1024 + c];

    #pragma unroll 1
    for (int vb = 0; vb < 32; vb += DPF) {
        #pragma unroll
        for (int i = 0; i < DPF; ++i) {                // static buf index
            float4 xv = buf[i];
            int nxt = vb + DPF + i;
            if (nxt < 32) buf[i] = base4[(size_t)nxt * 1024 + c];
            float4 yo;
#define SSL_STEP(XV, YOUT) { \
            float sx2 = fmaf(nhs, (XV), hst); \
            float u2  = fmaf(nq, Y, sx2); \
            float t2  = fminf(u2, 0.0f); \
            bool att  = sx2 < r * Y; \
            float af  = att ? a_af : a_sf; \
            float as2 = att ? a_as : a_ss; \
            EF = fmaf(af,  EF - t2, t2); \
            ES = fmaf(as2, ES - t2, t2); \
            Y  = EF + ES; \
            (YOUT) = Y; }
            SSL_STEP(xv.x, yo.x)
            SSL_STEP(xv.y, yo.y)
            SSL_STEP(xv.z, yo.z)
            SSL_STEP(xv.w, yo.w)
#undef SSL_STEP
            yr[(size_t)c * 32 + vb + i] = yo;
        }
    }
}

extern "C" void kernel_launch(void* const* d_in, const int* in_sizes, int n_in,
                              void* d_out, int out_size, void* d_ws, size_t ws_size,
                              hipStream_t stream) {
    const float* x = (const float*)d_in[0];
    const int B = in_sizes[0] / T_LEN;   // 128

    // ws: mp 8MB | pw 256B | xq 16MB (reused after map as bnd/Jv/gv) | xt 64MB
    const size_t MP_B = (size_t)B * NCM * SUB * K * sizeof(__half2);
    const size_t PW_O = MP_B;
    const size_t XQ_O = PW_O + 256;
    const size_t XQ_B = (size_t)B * QROW * sizeof(float);
    const size_t XT_O = XQ_O + XQ_B;

    __half2* mp  = (__half2*)d_ws;
    float*   pw  = (float*)((char*)d_ws + PW_O);
    float*   xq  = (float*)((char*)d_ws + XQ_O);
    float*   xt  = (float*)((char*)d_ws + XT_O);
    // xq region reuse (xq dead after ssl_map_q):
    float2*  bnd = (float2*)xq;                             // 1 MB
    float4*  Jv  = (float4*)((char*)xq + (1u << 20));       // 2 MB
    float2*  gv  = (float2*)((char*)xq + (3u << 20));       // 1 MB

    ssl_tr<<<16 * B, 256, 0, stream>>>(
        x, xt, xq, pw,
        (const float*)d_in[1], (const float*)d_in[2], (const float*)d_in[3],
        (const float*)d_in[4], (const float*)d_in[5], (const float*)d_in[6],
        (const float*)d_in[7]);

    int map_blocks = (B * NCM * K + 255) / 256;     // 512
    ssl_map_q<<<map_blocks, 256, 0, stream>>>(xq, mp, pw, B);

    ssl_guess<<<B, 1024, 0, stream>>>(mp, bnd, pw, B);

    for (int it = 0; it < NIT; ++it) {
        ssl_jac_g<<<4 * B, 256, 0, stream>>>(xt, bnd, Jv, gv, pw);
        ssl_scan_g<<<B, 1024, 0, stream>>>(Jv, gv, bnd);
    }

    ssl_out_g<<<4 * B, 256, 0, stream>>>(xt, (float*)d_out, bnd, pw);
}